// Round 9
// baseline (80.423 us; speedup 1.0000x reference)
//
#include <hip/hip_runtime.h>

#define NODES 512
#define WORDS 16          // 512 bits / 32
#define NBATCH 32
#define SENTINEL 11       // MAX_DISTANCE + 1
#define NEMB 12           // MAX_DISTANCE + 2
#define NOUT 8

// ---------------------------------------------------------------------------
// K1: pack adjacency bits, one u32 word (32 elements, 8x float4) per thread.
// node_mask (int32 on upload) ballot-packed into LDS once per block.
// ---------------------------------------------------------------------------
__global__ void __launch_bounds__(256)
pack_bits(const float* __restrict__ A, const int* __restrict__ mask,
          unsigned int* __restrict__ bitA) {
    const int tid = blockIdx.x * 256 + threadIdx.x;   // 262144 words total
    const int t = threadIdx.x;
    const int w = tid & 15;
    const int i = (tid >> 4) & 511;
    const int b = tid >> 13;                          // constant per block

    __shared__ unsigned int s_mw[WORDS];
    {
        bool m0 = mask[b * NODES + t] != 0;
        bool m1 = mask[b * NODES + 256 + t] != 0;
        unsigned long long b0 = __ballot(m0);
        unsigned long long b1 = __ballot(m1);
        if ((t & 63) == 0) {
            int wv = t >> 6;
            s_mw[2 * wv]         = (unsigned int)b0;
            s_mw[2 * wv + 1]     = (unsigned int)(b0 >> 32);
            s_mw[8 + 2 * wv]     = (unsigned int)b1;
            s_mw[8 + 2 * wv + 1] = (unsigned int)(b1 >> 32);
        }
    }

    const float4* p = (const float4*)(A + (size_t)tid * 32);
    unsigned int bits = 0;
#pragma unroll
    for (int q = 0; q < 8; ++q) {
        float4 v = p[q];
        bits |= (v.x > 0.5f ? 1u : 0u) << (4 * q);
        bits |= (v.y > 0.5f ? 1u : 0u) << (4 * q + 1);
        bits |= (v.z > 0.5f ? 1u : 0u) << (4 * q + 2);
        bits |= (v.w > 0.5f ? 1u : 0u) << (4 * q + 3);
    }
    __syncthreads();
    bool rv = (s_mw[i >> 5] >> (i & 31)) & 1u;
    bitA[tid] = rv ? (bits & s_mw[w]) : 0u;
}

// ---------------------------------------------------------------------------
// K2: symmetrize: adj[b,i,w] |= transpose bits (1 MB, L2-resident).
// ---------------------------------------------------------------------------
__global__ void __launch_bounds__(256)
symmetrize(const unsigned int* __restrict__ bitA, unsigned int* __restrict__ adjb) {
    int tid = blockIdx.x * 256 + threadIdx.x;   // total B*N*WORDS = 262144
    int w = tid & 15;
    int i = (tid >> 4) & 511;
    int b = tid >> 13;
    const unsigned int* base = bitA + (size_t)b * NODES * WORDS;
    unsigned int word = base[i * WORDS + w];
    unsigned int t = 0;
    int iw = i >> 5, ib = i & 31;
#pragma unroll
    for (int k = 0; k < 32; ++k) {
        t |= ((base[(32 * w + k) * WORDS + iw] >> ib) & 1u) << k;
    }
    adjb[tid] = word | t;
}

// ---------------------------------------------------------------------------
// K3: direct d<=2 shortest-path + embedding store. Block = (source i, batch),
// 256 threads, each handles columns t and t+256.
// Hot path needs NO BFS loop: d0 = (j==i); d1 = bit j of row_i (LDS
// broadcast); d2 = (row_j & row_i) != 0 (row_i wave-uniform from LDS ->
// conflict-free broadcast reads). One ballot checks saturation; the general
// double-buffered frontier loop (round-8 machinery) runs only as the cold
// fallback for t>=3 / disconnected cases. 2 barriers in the hot path.
// Small live set -> __launch_bounds__(256,8): 8 blocks/CU so neighbor
// blocks' store streams fully interleave.
// ---------------------------------------------------------------------------
__global__ void __launch_bounds__(256, 8)
bfs_store(const unsigned int* __restrict__ adjb, const int* __restrict__ mask,
          const float* __restrict__ emb, float4* __restrict__ out4) {
    const int i = blockIdx.x;
    const int b = blockIdx.y;
    const int t = threadIdx.x;
    const int cA = t, cB = t + 256;

    __shared__ unsigned int s_rowi[WORDS];
    __shared__ unsigned int s_f[2][WORDS];
    __shared__ unsigned int s_state[2][4];    // bit0 anyNew, bit1 allDone
    __shared__ unsigned char s_d8[NODES];
    __shared__ __align__(16) float s_emb[NEMB * NOUT];

    if (t < NEMB * NOUT) s_emb[t] = emb[t];

    const unsigned int* Ab = adjb + (size_t)b * NODES * WORDS;
    if (t < 4) ((uint4*)s_rowi)[t] = ((const uint4*)(Ab + (size_t)i * WORDS))[t];

    const bool valid_i = (mask[b * NODES + i] != 0);
    const bool validA  = (mask[b * NODES + cA] != 0);
    const bool validB  = (mask[b * NODES + cB] != 0);

    const uint4* rA = (const uint4*)(Ab + (size_t)cA * WORDS);
    const uint4* rB = (const uint4*)(Ab + (size_t)cB * WORDS);

    __syncthreads();   // s_rowi, s_emb visible

    uint4 i0 = ((const uint4*)s_rowi)[0], i1 = ((const uint4*)s_rowi)[1],
          i2 = ((const uint4*)s_rowi)[2], i3 = ((const uint4*)s_rowi)[3];

    uint4 a0 = rA[0], a1 = rA[1], a2 = rA[2], a3 = rA[3];
    unsigned int hA =
        (a0.x & i0.x) | (a0.y & i0.y) | (a0.z & i0.z) | (a0.w & i0.w) |
        (a1.x & i1.x) | (a1.y & i1.y) | (a1.z & i1.z) | (a1.w & i1.w) |
        (a2.x & i2.x) | (a2.y & i2.y) | (a2.z & i2.z) | (a2.w & i2.w) |
        (a3.x & i3.x) | (a3.y & i3.y) | (a3.z & i3.z) | (a3.w & i3.w);
    uint4 b0 = rB[0], b1 = rB[1], b2 = rB[2], b3 = rB[3];
    unsigned int hB =
        (b0.x & i0.x) | (b0.y & i0.y) | (b0.z & i0.z) | (b0.w & i0.w) |
        (b1.x & i1.x) | (b1.y & i1.y) | (b1.z & i1.z) | (b1.w & i1.w) |
        (b2.x & i2.x) | (b2.y & i2.y) | (b2.z & i2.z) | (b2.w & i2.w) |
        (b3.x & i3.x) | (b3.y & i3.y) | (b3.z & i3.z) | (b3.w & i3.w);

    unsigned int bit1A = (s_rowi[cA >> 5] >> (cA & 31)) & 1u;
    unsigned int bit1B = (s_rowi[cB >> 5] >> (cB & 31)) & 1u;

    int dA = (cA == i && valid_i) ? 0 : (bit1A ? 1 : (hA ? 2 : SENTINEL));
    int dB = (cB == i && valid_i) ? 0 : (bit1B ? 1 : (hB ? 2 : SENTINEL));

    // frontier (d==2) + saturation consensus
    {
        unsigned long long fA = __ballot(dA == 2);
        unsigned long long fB = __ballot(dB == 2);
        bool doneP = ((dA <= 2) || !validA) && ((dB <= 2) || !validB);
        unsigned long long balD = __ballot(doneP);
        int w = t >> 6;
        if ((t & 63) == 0) {
            s_f[0][2 * w]         = (unsigned int)fA;
            s_f[0][2 * w + 1]     = (unsigned int)(fA >> 32);
            s_f[0][8 + 2 * w]     = (unsigned int)fB;
            s_f[0][8 + 2 * w + 1] = (unsigned int)(fB >> 32);
            s_state[0][w] = (((fA | fB) != 0ull) ? 1u : 0u) |
                            ((balD == ~0ull) ? 2u : 0u);
        }
    }
    __syncthreads();
    unsigned int anyw = 0, donew = 2;
#pragma unroll
    for (int wv = 0; wv < 4; ++wv) {
        unsigned int st = s_state[0][wv];
        anyw |= st; donew &= st;
    }

    if ((anyw & 1u) && !(donew & 2u)) {
        // COLD fallback: general BFS t=3..10 (double-buffered frontier,
        // one barrier/hop). Rows reloaded from L2 to keep live set small.
        bool reachA = (dA != SENTINEL), reachB = (dB != SENTINEL);
        int p = 0;
        const int w = t >> 6;
        for (int tt = 3; tt <= 10; ++tt) {
            uint4 f0 = ((const uint4*)s_f[p])[0], f1 = ((const uint4*)s_f[p])[1],
                  f2 = ((const uint4*)s_f[p])[2], f3 = ((const uint4*)s_f[p])[3];
            uint4 x0 = rA[0], x1 = rA[1], x2 = rA[2], x3 = rA[3];
            unsigned int hitA =
                (x0.x & f0.x) | (x0.y & f0.y) | (x0.z & f0.z) | (x0.w & f0.w) |
                (x1.x & f1.x) | (x1.y & f1.y) | (x1.z & f1.z) | (x1.w & f1.w) |
                (x2.x & f2.x) | (x2.y & f2.y) | (x2.z & f2.z) | (x2.w & f2.w) |
                (x3.x & f3.x) | (x3.y & f3.y) | (x3.z & f3.z) | (x3.w & f3.w);
            uint4 y0 = rB[0], y1 = rB[1], y2 = rB[2], y3 = rB[3];
            unsigned int hitB =
                (y0.x & f0.x) | (y0.y & f0.y) | (y0.z & f0.z) | (y0.w & f0.w) |
                (y1.x & f1.x) | (y1.y & f1.y) | (y1.z & f1.z) | (y1.w & f1.w) |
                (y2.x & f2.x) | (y2.y & f2.y) | (y2.z & f2.z) | (y2.w & f2.w) |
                (y3.x & f3.x) | (y3.y & f3.y) | (y3.z & f3.z) | (y3.w & f3.w);
            bool newA = hitA && !reachA;
            bool newB = hitB && !reachB;
            unsigned long long nA = __ballot(newA);
            unsigned long long nB = __ballot(newB);
            bool dn = (reachA || newA || !validA) && (reachB || newB || !validB);
            unsigned long long bD = __ballot(dn);
            if ((t & 63) == 0) {
                s_f[p ^ 1][2 * w]         = (unsigned int)nA;
                s_f[p ^ 1][2 * w + 1]     = (unsigned int)(nA >> 32);
                s_f[p ^ 1][8 + 2 * w]     = (unsigned int)nB;
                s_f[p ^ 1][8 + 2 * w + 1] = (unsigned int)(nB >> 32);
                s_state[p ^ 1][w] = (((nA | nB) != 0ull) ? 1u : 0u) |
                                    ((bD == ~0ull) ? 2u : 0u);
            }
            if (newA) { reachA = true; dA = tt; }
            if (newB) { reachB = true; dB = tt; }
            __syncthreads();
            p ^= 1;
            unsigned int aw = 0, dw = 2;
#pragma unroll
            for (int wv = 0; wv < 4; ++wv) {
                unsigned int st = s_state[p][wv];
                aw |= st; dw &= st;
            }
            if (!(aw & 1u) || (dw & 2u)) break;
        }
    }

    // Epilogue: redistribute dist via LDS; 4 lane-contiguous float4 stores.
    s_d8[cA] = (unsigned char)dA;
    s_d8[cB] = (unsigned char)dB;
    __syncthreads();

    const float4* e4 = (const float4*)s_emb;
    size_t base = ((size_t)b * NODES + i) * (NODES * NOUT / 4);   // 1024 f4/row
#pragma unroll
    for (int q = 0; q < 4; ++q) {
        int k = t + 256 * q;
        int d = s_d8[k >> 1];
        out4[base + k] = e4[2 * d + (k & 1)];
    }
}

// ---------------------------------------------------------------------------
extern "C" void kernel_launch(void* const* d_in, const int* in_sizes, int n_in,
                              void* d_out, int out_size, void* d_ws, size_t ws_size,
                              hipStream_t stream) {
    const float* adjacency = (const float*)d_in[0];
    const int* node_mask = (const int*)d_in[1];   // bool -> int32 on upload
    const float* emb = (const float*)d_in[2];
    float4* out4 = (float4*)d_out;

    unsigned int* bitA = (unsigned int*)d_ws;                       // 1 MB
    unsigned int* adjb = bitA + (size_t)NBATCH * NODES * WORDS;     // 1 MB

    // K1: 262144 words -> 1024 blocks (each thread packs 32 adjacency elems)
    pack_bits<<<1024, 256, 0, stream>>>(adjacency, node_mask, bitA);
    // K2: 262144 words -> 1024 blocks
    symmetrize<<<1024, 256, 0, stream>>>(bitA, adjb);
    // K3: one block per (source, batch); direct d<=2 + cold BFS fallback
    bfs_store<<<dim3(NODES, NBATCH), 256, 0, stream>>>(adjb, node_mask, emb, out4);
}